// Round 1
// baseline (79.585 us; speedup 1.0000x reference)
//
#include <hip/hip_runtime.h>

// Problem constants (B=8, Cin=64, H=W=14, Cout=64, K=3, pad=1, stride=1)
#define NB   8
#define CIN  64
#define HW   14
#define COUT 64
#define NX   (NB*CIN*HW*HW)     // 100352 x elements
#define NW   (COUT*CIN*9)       // 36864 weight elements
#define NOUT (NB*COUT*HW*HW)    // 100352 outputs
#define NPAD (NB*60*64)         // 30720 pad cells in qx (60 border px/img * 64 ch)

// ws layout:
//   float part[80]                      @ 0    (blocks 0..63: x partial max, 64..79: w partial max)
//   int8  qx[8][16][16][64] (padded)    @ 512  (131072 B, channels-last)
//   int8  qw[64][3][3][64]              @ 512+131072 (36864 B, channels-last)
#define QX_OFF 512
#define QW_OFF (512 + NB*16*16*64)

__global__ __launch_bounds__(256) void absmax_kernel(const float* __restrict__ x,
                                                     const float* __restrict__ w,
                                                     float* __restrict__ part) {
    const int bid = blockIdx.x, tid = threadIdx.x;
    float m = 0.f;
    if (bid < 64) {
        const float4* p = (const float4*)x;
        const int n4 = NX / 4;                       // 25088
        for (int i = bid * 256 + tid; i < n4; i += 64 * 256) {
            float4 v = p[i];
            m = fmaxf(m, fmaxf(fmaxf(fabsf(v.x), fabsf(v.y)),
                               fmaxf(fabsf(v.z), fabsf(v.w))));
        }
    } else {
        const float4* p = (const float4*)w;
        const int n4 = NW / 4;                       // 9216
        for (int i = (bid - 64) * 256 + tid; i < n4; i += 16 * 256) {
            float4 v = p[i];
            m = fmaxf(m, fmaxf(fmaxf(fabsf(v.x), fabsf(v.y)),
                               fmaxf(fabsf(v.z), fabsf(v.w))));
        }
    }
    // wave64 butterfly-free down-reduce
    #pragma unroll
    for (int off = 32; off; off >>= 1)
        m = fmaxf(m, __shfl_down(m, off, 64));
    __shared__ float lds[4];
    if ((tid & 63) == 0) lds[tid >> 6] = m;
    __syncthreads();
    if (tid == 0)
        part[bid] = fmaxf(fmaxf(lds[0], lds[1]), fmaxf(lds[2], lds[3]));
}

__global__ __launch_bounds__(256) void quantize_kernel(const float* __restrict__ x,
                                                       const float* __restrict__ w,
                                                       const float* __restrict__ part,
                                                       char* __restrict__ qx,
                                                       char* __restrict__ qw) {
    // uniform scalar reduce of partials (compiler emits s_loads; L1-hot)
    float mx = 0.f, mw = 0.f;
    for (int i = 0; i < 64; ++i) mx = fmaxf(mx, part[i]);
    for (int i = 64; i < 80; ++i) mw = fmaxf(mw, part[i]);
    const float sx = mx / 127.0f, sw = mw / 127.0f;

    const int n = blockIdx.x * 256 + threadIdx.x;
    if (n < NX) {
        // interior: x linear [b][c][h][w] (coalesced read, byte scatter write)
        int w_ = n % 14, t = n / 14;
        int h = t % 14;  t /= 14;
        int c = t % 64;  int b = t / 64;
        int q = (int)rintf(x[n] / sx);           // rintf = round-half-even = jnp.round
        q = min(127, max(-128, q));
        qx[((b * 16 + h + 1) * 16 + (w_ + 1)) * 64 + c] = (char)q;
    } else if (n < NX + NPAD) {
        // zero the 60 border pixels per image (ws is poisoned 0xAA each launch)
        int j = n - NX;
        int c = j % 64; int p = (j / 64) % 60; int b = j / (64 * 60);
        int hh, ww;
        if      (p < 16) { hh = 0;      ww = p;      }
        else if (p < 32) { hh = 15;     ww = p - 16; }
        else if (p < 46) { hh = p - 31; ww = 0;      }   // hh in 1..14
        else             { hh = p - 45; ww = 15;     }   // hh in 1..14
        qx[((b * 16 + hh) * 16 + ww) * 64 + c] = 0;
    } else if (n < NX + NPAD + NW) {
        // weight linear [o][c][kh][kw] -> qw[o][kh][kw][c]
        int j = n - NX - NPAD;
        int kw = j % 3, t = j / 3;
        int kh = t % 3; t /= 3;
        int c  = t % 64; int o = t / 64;
        int q = (int)rintf(w[j] / sw);
        q = min(127, max(-128, q));
        qw[((o * 3 + kh) * 3 + kw) * 64 + c] = (char)q;
    }
}

__device__ __forceinline__ int dp4(int a, int b, int acc) {
    acc += (int)(signed char)(a)       * (int)(signed char)(b);
    acc += (int)(signed char)(a >> 8)  * (int)(signed char)(b >> 8);
    acc += (int)(signed char)(a >> 16) * (int)(signed char)(b >> 16);
    acc += (a >> 24)                   * (b >> 24);
    return acc;
}

__global__ __launch_bounds__(256) void conv_kernel(const char* __restrict__ qx,
                                                   const char* __restrict__ qw,
                                                   const float* __restrict__ part,
                                                   const float* __restrict__ bias,
                                                   float* __restrict__ out) {
    const int n = blockIdx.x * 256 + threadIdx.x;   // exact: 392*256 == NOUT
    float mx = 0.f, mw = 0.f;
    for (int i = 0; i < 64; ++i) mx = fmaxf(mx, part[i]);
    for (int i = 64; i < 80; ++i) mw = fmaxf(mw, part[i]);
    const float scale = (mx / 127.0f) * (mw / 127.0f);

    int w_ = n % 14, t = n / 14;
    int h = t % 14;  t /= 14;
    int o = t % 64;  int b = t / 64;

    const int4* wq = (const int4*)(qw + o * 9 * 64);
    int acc = 0;
    #pragma unroll
    for (int kh = 0; kh < 3; ++kh) {
        #pragma unroll
        for (int kw = 0; kw < 3; ++kw) {
            const int4* xq = (const int4*)(qx + ((b * 16 + h + kh) * 16 + (w_ + kw)) * 64);
            #pragma unroll
            for (int c4 = 0; c4 < 4; ++c4) {
                int4 xa = xq[c4];
                int4 wa = wq[(kh * 3 + kw) * 4 + c4];
                acc = dp4(xa.x, wa.x, acc);
                acc = dp4(xa.y, wa.y, acc);
                acc = dp4(xa.z, wa.z, acc);
                acc = dp4(xa.w, wa.w, acc);
            }
        }
    }
    out[n] = scale * (float)acc + bias[o];
}

extern "C" void kernel_launch(void* const* d_in, const int* in_sizes, int n_in,
                              void* d_out, int out_size, void* d_ws, size_t ws_size,
                              hipStream_t stream) {
    const float* x    = (const float*)d_in[0];
    const float* w    = (const float*)d_in[1];
    const float* bias = (const float*)d_in[2];
    // d_in[3] (lut) and d_in[4] (gradient_lut) are mathematically redundant:
    // lut[a+128][b+128] == a*b exactly, and the 576-term fp32 sum is exact
    // (|sum| < 2^24), so integer dot products are bit-identical.
    float* part = (float*)d_ws;
    char*  qx   = (char*)d_ws + QX_OFF;
    char*  qw   = (char*)d_ws + QW_OFF;
    float* out  = (float*)d_out;

    absmax_kernel  <<<80,  256, 0, stream>>>(x, w, part);
    quantize_kernel<<<656, 256, 0, stream>>>(x, w, part, qx, qw);
    conv_kernel    <<<392, 256, 0, stream>>>(qx, qw, part, bias, out);
}

// Round 2
// 78.372 us; speedup vs baseline: 1.0155x; 1.0155x over previous
//
#include <hip/hip_runtime.h>

// Problem constants (B=8, Cin=64, H=W=14, Cout=64, K=3, pad=1, stride=1)
#define NB   8
#define CIN  64
#define HW   14
#define COUT 64
#define NX   (NB*CIN*HW*HW)     // 100352 x elements
#define NW   (COUT*CIN*9)       // 36864 weight elements
#define NOUT (NB*COUT*HW*HW)    // 100352 outputs

// ws layout:
//   float part[80]                      @ 0    (blocks 0..63: x partial max, 64..79: w partial max)
//   int8  qx[8][16][16][64] (padded)    @ 512  (131072 B, channels-last)
//   int8  qw[64][3][3][64]              @ 512+131072 (36864 B, channels-last)
#define QX_OFF 512
#define QW_OFF (512 + NB*16*16*64)

__global__ __launch_bounds__(256) void absmax_kernel(const float* __restrict__ x,
                                                     const float* __restrict__ w,
                                                     float* __restrict__ part) {
    const int bid = blockIdx.x, tid = threadIdx.x;
    float m = 0.f;
    if (bid < 64) {
        const float4* p = (const float4*)x;
        const int n4 = NX / 4;                       // 25088
        for (int i = bid * 256 + tid; i < n4; i += 64 * 256) {
            float4 v = p[i];
            m = fmaxf(m, fmaxf(fmaxf(fabsf(v.x), fabsf(v.y)),
                               fmaxf(fabsf(v.z), fabsf(v.w))));
        }
    } else {
        const float4* p = (const float4*)w;
        const int n4 = NW / 4;                       // 9216
        for (int i = (bid - 64) * 256 + tid; i < n4; i += 16 * 256) {
            float4 v = p[i];
            m = fmaxf(m, fmaxf(fmaxf(fabsf(v.x), fabsf(v.y)),
                               fmaxf(fabsf(v.z), fabsf(v.w))));
        }
    }
    #pragma unroll
    for (int off = 32; off; off >>= 1)
        m = fmaxf(m, __shfl_down(m, off, 64));
    __shared__ float lds[4];
    if ((tid & 63) == 0) lds[tid >> 6] = m;
    __syncthreads();
    if (tid == 0)
        part[bid] = fmaxf(fmaxf(lds[0], lds[1]), fmaxf(lds[2], lds[3]));
}

__device__ __forceinline__ float reduce_part(const float* __restrict__ part, int lo, int hi) {
    float m = 0.f;
    for (int i = lo; i < hi; ++i) m = fmaxf(m, part[i]);  // uniform -> s_loads
    return m;
}

__device__ __forceinline__ signed char quant1(float v, float s) {
    int q = (int)rintf(v / s);                  // rintf = round-half-even = jnp.round
    return (signed char)min(127, max(-128, q));
}

// work items: 25088 x-float4 | 7680 pad-dwords | 9216 w-float4  = 41984 = 164*256
__global__ __launch_bounds__(256) void quantize_kernel(const float* __restrict__ x,
                                                       const float* __restrict__ w,
                                                       const float* __restrict__ part,
                                                       char* __restrict__ qx,
                                                       char* __restrict__ qw) {
    const float sx = reduce_part(part, 0, 64) / 127.0f;
    const float sw = reduce_part(part, 64, 80) / 127.0f;

    const int n = blockIdx.x * 256 + threadIdx.x;
    if (n < 25088) {
        float4 v = ((const float4*)x)[n];
        const float vv[4] = {v.x, v.y, v.z, v.w};
        #pragma unroll
        for (int e = 0; e < 4; ++e) {
            int idx = n * 4 + e;                 // linear [b][c][h][w]
            int ww = idx % 14, t = idx / 14;
            int h  = t % 14;   t /= 14;
            int c  = t % 64;   int b = t / 64;
            qx[((b * 16 + h + 1) * 16 + (ww + 1)) * 64 + c] = quant1(vv[e], sx);
        }
    } else if (n < 32768) {
        // zero the 60 border pixels per image as dwords (ws poisoned 0xAA)
        int j = n - 25088;
        int c4 = j % 16; int p = (j / 16) % 60; int b = j / 960;
        int hh, wwp;
        if      (p < 16) { hh = 0;      wwp = p;      }
        else if (p < 32) { hh = 15;     wwp = p - 16; }
        else if (p < 46) { hh = p - 31; wwp = 0;      }   // hh in 1..14
        else             { hh = p - 45; wwp = 15;     }   // hh in 1..14
        ((unsigned int*)qx)[(((b * 16 + hh) * 16 + wwp) * 64) / 4 + c4] = 0u;
    } else {
        int j4 = n - 32768;
        float4 v = ((const float4*)w)[j4];
        const float vv[4] = {v.x, v.y, v.z, v.w};
        #pragma unroll
        for (int e = 0; e < 4; ++e) {
            int idx = j4 * 4 + e;                // linear [o][c][kh][kw]
            int kw = idx % 3, t = idx / 3;
            int kh = t % 3;   t /= 3;
            int c  = t % 64;  int o = t / 64;
            qw[((o * 3 + kh) * 3 + kw) * 64 + c] = quant1(vv[e], sw);
        }
    }
}

__device__ __forceinline__ int dot4(int a, int b, int acc) {
#if __has_builtin(__builtin_amdgcn_sdot4)
    return __builtin_amdgcn_sdot4(a, b, acc, false);   // v_dot4_i32_i8
#else
    acc += (int)(signed char)(a)       * (int)(signed char)(b);
    acc += (int)(signed char)(a >> 8)  * (int)(signed char)(b >> 8);
    acc += (int)(signed char)(a >> 16) * (int)(signed char)(b >> 16);
    acc += (a >> 24)                   * (b >> 24);
    return acc;
#endif
}

__global__ __launch_bounds__(256) void conv_kernel(const char* __restrict__ qx,
                                                   const char* __restrict__ qw,
                                                   const float* __restrict__ part,
                                                   const float* __restrict__ bias,
                                                   float* __restrict__ out) {
    const int n = blockIdx.x * 256 + threadIdx.x;   // exact: 392*256 == NOUT
    const float scale = (reduce_part(part, 0, 64) / 127.0f) *
                        (reduce_part(part, 64, 80) / 127.0f);

    int w_ = n % 14, t = n / 14;
    int h = t % 14;  t /= 14;
    int o = t % 64;  int b = t / 64;

    const int4* wq = (const int4*)(qw + o * 9 * 64);
    // 4 independent accumulator chains (one per 16-channel chunk) for ILP
    int acc0 = 0, acc1 = 0, acc2 = 0, acc3 = 0;
    #pragma unroll
    for (int kh = 0; kh < 3; ++kh) {
        #pragma unroll
        for (int kw = 0; kw < 3; ++kw) {
            const int4* xq = (const int4*)(qx + ((b * 16 + h + kh) * 16 + (w_ + kw)) * 64);
            int4 xa0 = xq[0], xa1 = xq[1], xa2 = xq[2], xa3 = xq[3];
            int4 wa0 = wq[(kh * 3 + kw) * 4 + 0];
            int4 wa1 = wq[(kh * 3 + kw) * 4 + 1];
            int4 wa2 = wq[(kh * 3 + kw) * 4 + 2];
            int4 wa3 = wq[(kh * 3 + kw) * 4 + 3];
            acc0 = dot4(xa0.x, wa0.x, acc0); acc0 = dot4(xa0.y, wa0.y, acc0);
            acc0 = dot4(xa0.z, wa0.z, acc0); acc0 = dot4(xa0.w, wa0.w, acc0);
            acc1 = dot4(xa1.x, wa1.x, acc1); acc1 = dot4(xa1.y, wa1.y, acc1);
            acc1 = dot4(xa1.z, wa1.z, acc1); acc1 = dot4(xa1.w, wa1.w, acc1);
            acc2 = dot4(xa2.x, wa2.x, acc2); acc2 = dot4(xa2.y, wa2.y, acc2);
            acc2 = dot4(xa2.z, wa2.z, acc2); acc2 = dot4(xa2.w, wa2.w, acc2);
            acc3 = dot4(xa3.x, wa3.x, acc3); acc3 = dot4(xa3.y, wa3.y, acc3);
            acc3 = dot4(xa3.z, wa3.z, acc3); acc3 = dot4(xa3.w, wa3.w, acc3);
        }
    }
    int acc = (acc0 + acc1) + (acc2 + acc3);
    out[n] = scale * (float)acc + bias[o];
}

extern "C" void kernel_launch(void* const* d_in, const int* in_sizes, int n_in,
                              void* d_out, int out_size, void* d_ws, size_t ws_size,
                              hipStream_t stream) {
    const float* x    = (const float*)d_in[0];
    const float* w    = (const float*)d_in[1];
    const float* bias = (const float*)d_in[2];
    // d_in[3] (lut) and d_in[4] (gradient_lut) are mathematically redundant:
    // lut[a+128][b+128] == a*b exactly, and the 576-term fp32 sum is exact
    // (|sum| < 2^24), so integer dot products are bit-identical.
    float* part = (float*)d_ws;
    char*  qx   = (char*)d_ws + QX_OFF;
    char*  qw   = (char*)d_ws + QW_OFF;
    float* out  = (float*)d_out;

    absmax_kernel  <<<80,  256, 0, stream>>>(x, w, part);
    quantize_kernel<<<164, 256, 0, stream>>>(x, w, part, qx, qw);
    conv_kernel    <<<392, 256, 0, stream>>>(qx, qw, part, bias, out);
}

// Round 4
// 75.320 us; speedup vs baseline: 1.0566x; 1.0405x over previous
//
#include <hip/hip_runtime.h>

// Problem constants (B=8, Cin=64, H=W=14, Cout=64, K=3, pad=1, stride=1)
#define NB   8
#define CIN  64
#define HW   14
#define COUT 64
#define NX   (NB*CIN*HW*HW)     // 100352 x elements  (25088 float4)
#define NW   (COUT*CIN*9)       // 36864 weight elements (9216 float4)

// ws layout: float part[80] @ 0 — blocks 0..63: x partial max, 64..79: w
// partial max. Every slot written every launch (no init / atomics needed).

__global__ __launch_bounds__(256) void absmax_kernel(const float* __restrict__ x,
                                                     const float* __restrict__ w,
                                                     float* __restrict__ part) {
    const int bid = blockIdx.x, tid = threadIdx.x;
    float m = 0.f;
    if (bid < 64) {
        const float4* p = (const float4*)x;
        for (int i = bid * 256 + tid; i < NX / 4; i += 64 * 256) {   // 25088 f4
            float4 v = p[i];
            m = fmaxf(m, fmaxf(fmaxf(fabsf(v.x), fabsf(v.y)),
                               fmaxf(fabsf(v.z), fabsf(v.w))));
        }
    } else {
        const float4* p = (const float4*)w;
        for (int i = (bid - 64) * 256 + tid; i < NW / 4; i += 16 * 256) { // 9216
            float4 v = p[i];
            m = fmaxf(m, fmaxf(fmaxf(fabsf(v.x), fabsf(v.y)),
                               fmaxf(fabsf(v.z), fabsf(v.w))));
        }
    }
    #pragma unroll
    for (int off = 32; off; off >>= 1)
        m = fmaxf(m, __shfl_down(m, off, 64));
    __shared__ float lds[4];
    if ((tid & 63) == 0) lds[tid >> 6] = m;
    __syncthreads();
    if (tid == 0)
        part[bid] = fmaxf(fmaxf(lds[0], lds[1]), fmaxf(lds[2], lds[3]));
}

__device__ __forceinline__ float reduce_part(const float* __restrict__ part, int lo, int hi) {
    float m = 0.f;
    for (int i = lo; i < hi; ++i) m = fmaxf(m, part[i]);  // uniform -> s_loads
    return m;
}

__device__ __forceinline__ signed char quant1(float v, float s) {
    int q = (int)rintf(v / s);            // rintf = round-half-even = jnp.round
    return (signed char)min(127, max(-128, q));
}

__device__ __forceinline__ int dot4(int a, int b, int acc) {
#if __has_builtin(__builtin_amdgcn_sdot4)
    return __builtin_amdgcn_sdot4(a, b, acc, false);   // v_dot4_i32_i8
#else
    acc += (int)(signed char)(a)       * (int)(signed char)(b);
    acc += (int)(signed char)(a >> 8)  * (int)(signed char)(b >> 8);
    acc += (int)(signed char)(a >> 16) * (int)(signed char)(b >> 16);
    acc += (a >> 24)                   * (b >> 24);
    return acc;
#endif
}

// One block = (image, pair-of-output-channels). Self-contained: quantizes its
// image into padded LDS tile + its 2 couts' weights into LDS, then convolves.
__global__ __launch_bounds__(256) void fused_kernel(const float* __restrict__ x,
                                                    const float* __restrict__ w,
                                                    const float* __restrict__ part,
                                                    const float* __restrict__ bias,
                                                    float* __restrict__ out) {
    __shared__ int qx_i[16 * 16 * 16];          // padded [16][16][64] int8 = 16 KB
    __shared__ int qw_i[2 * 9 * 16];            // [2 couts][9 taps][64 c] int8
    char* qxl = (char*)qx_i;
    char* qwl = (char*)qw_i;

    const int tid = threadIdx.x;
    const int img = blockIdx.x >> 5;            // 8 images
    const int o0  = (blockIdx.x & 31) * 2;      // 32 cout-pairs

    const float sx = reduce_part(part, 0, 64) / 127.0f;
    const float sw = reduce_part(part, 64, 80) / 127.0f;

    // zero qx tile (borders must be 0; interior overwritten below)
    #pragma unroll
    for (int k = 0; k < 16; ++k) qx_i[tid + k * 256] = 0;
    __syncthreads();

    // quantize image img: 3136 float4
    const float4* xb = (const float4*)(x + img * (CIN * HW * HW));
    for (int k = 0; k < 13; ++k) {
        int i = tid + k * 256;
        if (i < 3136) {
            float4 v = xb[i];
            const float vv[4] = {v.x, v.y, v.z, v.w};
            #pragma unroll
            for (int e = 0; e < 4; ++e) {
                int idx = i * 4 + e;            // [c][h][w] within image
                int c = idx / 196, r = idx - c * 196;
                int h = r / 14,  ww = r - h * 14;
                qxl[((h + 1) * 16 + (ww + 1)) * 64 + c] = quant1(vv[e], sx);
            }
        }
    }
    // quantize weights for couts o0, o0+1: 288 float4 of w-linear [o][c][kh][kw]
    {
        int j4 = tid;                            // 288 = 256 + 32
        #pragma unroll
        for (int rep = 0; rep < 2; ++rep) {
            if (j4 < 288) {
                float4 v = ((const float4*)w)[o0 * 144 + j4];
                const float vv[4] = {v.x, v.y, v.z, v.w};
                #pragma unroll
                for (int e = 0; e < 4; ++e) {
                    int j = j4 * 4 + e;          // within [2][576]
                    int ol = j / 576, r = j - ol * 576;
                    int c = r / 9, rr = r - c * 9;
                    qwl[((ol * 9 + rr) * 64) + c] = quant1(vv[e], sw);
                }
            }
            j4 += 256;
        }
    }
    __syncthreads();

    // conv: thread = pixel (196 active), 2 couts, 4 acc chains each
    if (tid < 196) {
        int h = tid / 14, ww = tid - h * 14;
        int a0 = 0, a1 = 0, a2 = 0, a3 = 0;      // cout o0
        int b0 = 0, b1 = 0, b2 = 0, b3 = 0;      // cout o0+1
        #pragma unroll
        for (int kh = 0; kh < 3; ++kh) {
            #pragma unroll
            for (int kw = 0; kw < 3; ++kw) {
                const int4* xq = (const int4*)(qxl + ((h + kh) * 16 + (ww + kw)) * 64);
                int4 x0 = xq[0], x1 = xq[1], x2 = xq[2], x3 = xq[3];
                const int4* wq0 = (const int4*)(qwl + (kh * 3 + kw) * 64);
                const int4* wq1 = (const int4*)(qwl + (9 + kh * 3 + kw) * 64);
                int4 wa0 = wq0[0], wa1 = wq0[1], wa2 = wq0[2], wa3 = wq0[3];
                int4 wb0 = wq1[0], wb1 = wq1[1], wb2 = wq1[2], wb3 = wq1[3];
                a0 = dot4(x0.x, wa0.x, a0); a0 = dot4(x0.y, wa0.y, a0);
                a0 = dot4(x0.z, wa0.z, a0); a0 = dot4(x0.w, wa0.w, a0);
                a1 = dot4(x1.x, wa1.x, a1); a1 = dot4(x1.y, wa1.y, a1);
                a1 = dot4(x1.z, wa1.z, a1); a1 = dot4(x1.w, wa1.w, a1);
                a2 = dot4(x2.x, wa2.x, a2); a2 = dot4(x2.y, wa2.y, a2);
                a2 = dot4(x2.z, wa2.z, a2); a2 = dot4(x2.w, wa2.w, a2);
                a3 = dot4(x3.x, wa3.x, a3); a3 = dot4(x3.y, wa3.y, a3);
                a3 = dot4(x3.w, wa3.w, a3); a3 = dot4(x3.z, wa3.z, a3);
                b0 = dot4(x0.x, wb0.x, b0); b0 = dot4(x0.y, wb0.y, b0);
                b0 = dot4(x0.z, wb0.z, b0); b0 = dot4(x0.w, wb0.w, b0);
                b1 = dot4(x1.x, wb1.x, b1); b1 = dot4(x1.y, wb1.y, b1);
                b1 = dot4(x1.z, wb1.z, b1); b1 = dot4(x1.w, wb1.w, b1);
                b2 = dot4(x2.x, wb2.x, b2); b2 = dot4(x2.y, wb2.y, b2);
                b2 = dot4(x2.z, wb2.z, b2); b2 = dot4(x2.w, wb2.w, b2);
                b3 = dot4(x3.x, wb3.x, b3); b3 = dot4(x3.y, wb3.y, b3);
                b3 = dot4(x3.z, wb3.z, b3); b3 = dot4(x3.w, wb3.w, b3);
            }
        }
        const float s = sx * sw;
        int accA = (a0 + a1) + (a2 + a3);
        int accB = (b0 + b1) + (b2 + b3);
        out[(img * 64 + o0) * 196 + tid]     = s * (float)accA + bias[o0];
        out[(img * 64 + o0 + 1) * 196 + tid] = s * (float)accB + bias[o0 + 1];
    }
}

extern "C" void kernel_launch(void* const* d_in, const int* in_sizes, int n_in,
                              void* d_out, int out_size, void* d_ws, size_t ws_size,
                              hipStream_t stream) {
    const float* x    = (const float*)d_in[0];
    const float* w    = (const float*)d_in[1];
    const float* bias = (const float*)d_in[2];
    // d_in[3] (lut) and d_in[4] (gradient_lut) are mathematically redundant:
    // lut[a+128][b+128] == a*b exactly, and the 576-term fp32 sum is exact
    // (|sum| < 2^24), so integer dot products are bit-identical.
    float* part = (float*)d_ws;
    float* out  = (float*)d_out;

    absmax_kernel<<<80,  256, 0, stream>>>(x, w, part);
    fused_kernel <<<256, 256, 0, stream>>>(x, w, part, bias, out);
}

// Round 7
// 72.312 us; speedup vs baseline: 1.1006x; 1.0416x over previous
//
#include <hip/hip_runtime.h>

// Problem constants (B=8, Cin=64, H=W=14, Cout=64, K=3, pad=1, stride=1)
#define NB   8
#define CIN  64
#define HW   14
#define COUT 64
#define NX   (NB*CIN*HW*HW)     // 100352 x elements  (25088 float4)
#define NW   (COUT*CIN*9)       // 36864 weight elements (9216 float4)

// ws layout: float part[80] @ 0 — blocks 0..63: x partial max, 64..79: w
// partial max. Every slot written every launch (no init / atomics needed).

__global__ __launch_bounds__(256) void absmax_kernel(const float* __restrict__ x,
                                                     const float* __restrict__ w,
                                                     float* __restrict__ part) {
    const int bid = blockIdx.x, tid = threadIdx.x;
    float m = 0.f;
    if (bid < 64) {
        const float4* p = (const float4*)x;
        for (int i = bid * 256 + tid; i < NX / 4; i += 64 * 256) {   // 25088 f4
            float4 v = p[i];
            m = fmaxf(m, fmaxf(fmaxf(fabsf(v.x), fabsf(v.y)),
                               fmaxf(fabsf(v.z), fabsf(v.w))));
        }
    } else {
        const float4* p = (const float4*)w;
        for (int i = (bid - 64) * 256 + tid; i < NW / 4; i += 16 * 256) { // 9216
            float4 v = p[i];
            m = fmaxf(m, fmaxf(fmaxf(fabsf(v.x), fabsf(v.y)),
                               fmaxf(fabsf(v.z), fabsf(v.w))));
        }
    }
    #pragma unroll
    for (int off = 32; off; off >>= 1)
        m = fmaxf(m, __shfl_down(m, off, 64));
    __shared__ float lds[4];
    if ((tid & 63) == 0) lds[tid >> 6] = m;
    __syncthreads();
    if (tid == 0)
        part[bid] = fmaxf(fmaxf(lds[0], lds[1]), fmaxf(lds[2], lds[3]));
}

__device__ __forceinline__ float reduce_part(const float* __restrict__ part, int lo, int hi) {
    float m = 0.f;
    for (int i = lo; i < hi; ++i) m = fmaxf(m, part[i]);  // uniform -> s_loads
    return m;
}

__device__ __forceinline__ signed char quant1(float v, float s) {
    int q = (int)rintf(v / s);            // rintf = round-half-even = jnp.round
    return (signed char)min(127, max(-128, q));
}

__device__ __forceinline__ int dot4(int a, int b, int acc) {
#if __has_builtin(__builtin_amdgcn_sdot4)
    return __builtin_amdgcn_sdot4(a, b, acc, false);   // v_dot4_i32_i8
#else
    acc += (int)(signed char)(a)       * (int)(signed char)(b);
    acc += (int)(signed char)(a >> 8)  * (int)(signed char)(b >> 8);
    acc += (int)(signed char)(a >> 16) * (int)(signed char)(b >> 16);
    acc += (a >> 24)                   * (b >> 24);
    return acc;
#endif
}

// One block = (image, pair-of-output-channels), 512 threads (8 waves = 2/SIMD).
// qx LDS rows padded to 68 B (17 dw): gcd(17,32)=1 -> consecutive-px lanes
// sweep all 32 banks -> ~2-way (free) on the conv dword reads. The 4-B-only
// alignment of 68-B rows also stops the compiler from merging reads back into
// (32-way-conflicting) b128s.
__global__ __launch_bounds__(512) void fused_kernel(const float* __restrict__ x,
                                                    const float* __restrict__ w,
                                                    const float* __restrict__ part,
                                                    const float* __restrict__ bias,
                                                    float* __restrict__ out) {
    __shared__ int qx_d[256 * 17];              // [256 px-rows][17 dw] = 17408 B
    __shared__ int qw_i[2 * 9 * 16];            // [2 couts][9 taps][64 ch] int8
    char* qxl = (char*)qx_d;
    char* qwl = (char*)qw_i;

    const int tid = threadIdx.x;
    const int img = blockIdx.x >> 5;            // 8 images
    const int o0  = (blockIdx.x & 31) * 2;      // 32 cout-pairs

    const float sx = reduce_part(part, 0, 64) / 127.0f;
    const float sw = reduce_part(part, 64, 80) / 127.0f;

    // zero qx tile incl. padding (borders must be 0; interior overwritten)
    #pragma unroll
    for (int k = 0; k < 9; ++k) {
        int i = tid + k * 512;
        if (i < 256 * 17) qx_d[i] = 0;
    }
    __syncthreads();

    // quantize image img: 3136 float4 (coalesced global, byte scatter to LDS)
    const float4* xb = (const float4*)(x + img * (CIN * HW * HW));
    #pragma unroll
    for (int k = 0; k < 7; ++k) {
        int i = tid + k * 512;
        if (i < 3136) {
            float4 v = xb[i];
            const float vv[4] = {v.x, v.y, v.z, v.w};
            #pragma unroll
            for (int e = 0; e < 4; ++e) {
                int idx = i * 4 + e;            // [c][h][w] within image
                int c = idx / 196, r = idx - c * 196;
                int h = r / 14,  ww = r - h * 14;
                qxl[((h + 1) * 16 + (ww + 1)) * 68 + c] = quant1(vv[e], sx);
            }
        }
    }
    // quantize weights for couts o0, o0+1: 288 float4 of w-linear [o][c][kh][kw]
    if (tid < 288) {
        float4 v = ((const float4*)w)[o0 * 144 + tid];
        const float vv[4] = {v.x, v.y, v.z, v.w};
        #pragma unroll
        for (int e = 0; e < 4; ++e) {
            int j = tid * 4 + e;                 // within [2][576]
            int ol = j / 576, r2 = j - ol * 576;
            int c = r2 / 9, tap = r2 - c * 9;
            qwl[((ol * 9 + tap) * 64) + c] = quant1(vv[e], sw);
        }
    }
    __syncthreads();

    // conv: 392 items = (cout-of-pair, pixel); thread t -> item t
    if (tid < 392) {
        const int ol = (tid >= 196) ? 1 : 0;
        const int px = tid - ol * 196;
        const int h = px / 14, ww = px - h * 14;
        int a0 = 0, a1 = 0, a2 = 0, a3 = 0;      // 4 independent chains
        #pragma unroll
        for (int kh = 0; kh < 3; ++kh) {
            #pragma unroll
            for (int kw = 0; kw < 3; ++kw) {
                const int* xr = qx_d + ((h + kh) * 16 + (ww + kw)) * 17;
                const int4* wr = ((const int4*)qw_i) + (ol * 9 + kh * 3 + kw) * 4;
                int4 w0 = wr[0], w1 = wr[1], w2 = wr[2], w3 = wr[3];
                a0 = dot4(xr[0],  w0.x, a0); a1 = dot4(xr[1],  w0.y, a1);
                a2 = dot4(xr[2],  w0.z, a2); a3 = dot4(xr[3],  w0.w, a3);
                a0 = dot4(xr[4],  w1.x, a0); a1 = dot4(xr[5],  w1.y, a1);
                a2 = dot4(xr[6],  w1.z, a2); a3 = dot4(xr[7],  w1.w, a3);
                a0 = dot4(xr[8],  w2.x, a0); a1 = dot4(xr[9],  w2.y, a1);
                a2 = dot4(xr[10], w2.z, a2); a3 = dot4(xr[11], w2.w, a3);
                a0 = dot4(xr[12], w3.x, a0); a1 = dot4(xr[13], w3.y, a1);
                a2 = dot4(xr[14], w3.z, a2); a3 = dot4(xr[15], w3.w, a3);
            }
        }
        const int acc = (a0 + a1) + (a2 + a3);
        const int oc = o0 + ol;
        out[(img * 64 + oc) * 196 + px] = (sx * sw) * (float)acc + bias[oc];
    }
}

extern "C" void kernel_launch(void* const* d_in, const int* in_sizes, int n_in,
                              void* d_out, int out_size, void* d_ws, size_t ws_size,
                              hipStream_t stream) {
    const float* x    = (const float*)d_in[0];
    const float* w    = (const float*)d_in[1];
    const float* bias = (const float*)d_in[2];
    // d_in[3] (lut) and d_in[4] (gradient_lut) are mathematically redundant:
    // lut[a+128][b+128] == a*b exactly, and the 576-term fp32 sum is exact
    // (|sum| < 2^24), so integer dot products are bit-identical.
    float* part = (float*)d_ws;
    float* out  = (float*)d_out;

    absmax_kernel<<<80,  256, 0, stream>>>(x, w, part);
    fused_kernel <<<256, 512, 0, stream>>>(x, w, part, bias, out);
}